// Round 2
// baseline (617.693 us; speedup 1.0000x reference)
//
#include <hip/hip_runtime.h>

// ChebConv K=3 GCN on MI355X — Round 2: CSR-gather, zero fp32 atomics.
// R1 post-mortem: each scatter pass emitted 51.2M device-scope fp32 atomics
// = 200MB of uncoalescible 4B write transactions (WRITE_SIZE matched exactly).
// Fix: counting-sort edges by dst into CSR (e_src), then gather per node.
// Fusions: norm applied on the fly in gathers; X1 epilogue in prop1;
// X2 + [X0|X1|X2]@W^T + relu in prop2 (16-lane shfl reduction).

#define NN 100000
#define NE 3200000
#define F  16
#define NB ((NN + 255) / 256)   // 391 blocks of 256

__global__ void k_deg(const int* __restrict__ dst, int* __restrict__ deg) {
    int e = blockIdx.x * blockDim.x + threadIdx.x;
    if (e < NE) atomicAdd(&deg[dst[e]], 1);
}

__global__ void k_norm(const int* __restrict__ deg, float* __restrict__ norm) {
    int n = blockIdx.x * blockDim.x + threadIdx.x;
    if (n < NN) {
        int d = deg[n];
        norm[n] = rsqrtf((float)(d < 1 ? 1 : d));
    }
}

// Per-block sums of deg for the 3-kernel exclusive scan.
__global__ void k_bsum(const int* __restrict__ deg, int* __restrict__ bsum) {
    __shared__ int s[256];
    int i = blockIdx.x * 256 + threadIdx.x;
    s[threadIdx.x] = (i < NN) ? deg[i] : 0;
    __syncthreads();
    for (int o = 128; o > 0; o >>= 1) {
        if (threadIdx.x < o) s[threadIdx.x] += s[threadIdx.x + o];
        __syncthreads();
    }
    if (threadIdx.x == 0) bsum[blockIdx.x] = s[0];
}

// Single-block exclusive scan of the 391 block sums.
__global__ void k_scan_bsum(int* __restrict__ bsum) {
    __shared__ int tmp[512];
    int t = threadIdx.x;
    tmp[t] = (t < NB) ? bsum[t] : 0;
    __syncthreads();
    for (int o = 1; o < 512; o <<= 1) {
        int add = (t >= o) ? tmp[t - o] : 0;
        __syncthreads();
        tmp[t] += add;
        __syncthreads();
    }
    if (t < NB) bsum[t] = (t == 0) ? 0 : tmp[t - 1];
}

// In-place: cur[] holds deg on entry, exclusive bucket offsets on exit.
// (Each block reads its own 256-chunk before writing it — no cross-block hazard.)
__global__ void k_scan(const int* __restrict__ bsum, int* __restrict__ cur) {
    __shared__ int tmp[256];
    int t = threadIdx.x, b = blockIdx.x;
    int i = b * 256 + t;
    int v = (i < NN) ? cur[i] : 0;
    tmp[t] = v;
    __syncthreads();
    for (int o = 1; o < 256; o <<= 1) {
        int add = (t >= o) ? tmp[t - o] : 0;
        __syncthreads();
        tmp[t] += add;
        __syncthreads();
    }
    if (i < NN) cur[i] = bsum[b] + tmp[t] - v;   // exclusive offset
}

// Bucket fill. After this, cur[n] == end offset of bucket n (== off[n+1]).
__global__ void k_fill(const int* __restrict__ src, const int* __restrict__ dst,
                       int* __restrict__ cur, int* __restrict__ e_src) {
    int e = blockIdx.x * blockDim.x + threadIdx.x;
    if (e >= NE) return;
    int pos = atomicAdd(&cur[dst[e]], 1);
    e_src[pos] = src[e];
}

// Gather pass 1: acc = sum over in-edges of X0[s]*norm[s]; X1 = -r*nv*acc + (r-1)*X0.
// 16 lanes per node; lane f owns feature f. Edge indices + src-norms fetched
// cooperatively (lane-parallel) then shfl-broadcast within the 16-lane group.
__global__ void k_prop1(const int* __restrict__ cur, const int* __restrict__ e_src,
                        const float* __restrict__ X0, const float* __restrict__ norm,
                        const float* __restrict__ lm, float* __restrict__ X1) {
    int tid = blockIdx.x * blockDim.x + threadIdx.x;
    int n = tid >> 4, f = tid & 15;
    if (n >= NN) return;
    int beg = (n == 0) ? 0 : cur[n - 1];
    int end = cur[n];
    float acc = 0.f;
    for (int e0 = beg; e0 < end; e0 += 16) {
        int m = end - e0;
        int cnt = m < 16 ? m : 16;
        int   idx = (f < cnt) ? e_src[e0 + f] : 0;
        float nw  = (f < cnt) ? norm[idx] : 0.f;
        for (int j = 0; j < cnt; ++j) {
            int   s = __shfl(idx, j, 16);
            float w = __shfl(nw, j, 16);
            acc += X0[(size_t)s * F + f] * w;   // 16 lanes -> one 64B line
        }
    }
    float r  = 2.0f / lm[0];
    float nv = norm[n];
    float x0 = X0[(size_t)n * F + f];
    X1[(size_t)n * F + f] = -r * (nv * acc) + (r - 1.0f) * x0;
}

// Gather pass 2 + epilogue: acc over X1[s]*norm[s];
// X2 = -2r*nv*acc + 2(r-1)*X1 - X0; out = relu([X0|X1|X2] @ W^T).
__global__ void k_prop2(const int* __restrict__ cur, const int* __restrict__ e_src,
                        const float* __restrict__ X0, const float* __restrict__ X1,
                        const float* __restrict__ norm, const float* __restrict__ lm,
                        const float* __restrict__ W, float* __restrict__ out) {
    __shared__ float Ws[96];
    if (threadIdx.x < 96) Ws[threadIdx.x] = W[threadIdx.x];
    __syncthreads();
    int tid = blockIdx.x * blockDim.x + threadIdx.x;
    int n = tid >> 4, f = tid & 15;
    if (n >= NN) return;
    int beg = (n == 0) ? 0 : cur[n - 1];
    int end = cur[n];
    float acc = 0.f;
    for (int e0 = beg; e0 < end; e0 += 16) {
        int m = end - e0;
        int cnt = m < 16 ? m : 16;
        int   idx = (f < cnt) ? e_src[e0 + f] : 0;
        float nw  = (f < cnt) ? norm[idx] : 0.f;
        for (int j = 0; j < cnt; ++j) {
            int   s = __shfl(idx, j, 16);
            float w = __shfl(nw, j, 16);
            acc += X1[(size_t)s * F + f] * w;
        }
    }
    float r  = 2.0f / lm[0];
    float nv = norm[n];
    float x0 = X0[(size_t)n * F + f];
    float x1 = X1[(size_t)n * F + f];
    float x2 = -2.0f * r * (nv * acc) + 2.0f * (r - 1.0f) * x1 - x0;
    float t0 = Ws[f] * x0 + Ws[16 + f] * x1 + Ws[32 + f] * x2;
    float t1 = Ws[48 + f] * x0 + Ws[64 + f] * x1 + Ws[80 + f] * x2;
    for (int o = 8; o >= 1; o >>= 1) {
        t0 += __shfl_xor(t0, o, 16);
        t1 += __shfl_xor(t1, o, 16);
    }
    if (f == 0) {
        out[(size_t)n * 2 + 0] = fmaxf(t0, 0.f);
        out[(size_t)n * 2 + 1] = fmaxf(t1, 0.f);
    }
}

extern "C" void kernel_launch(void* const* d_in, const int* in_sizes, int n_in,
                              void* d_out, int out_size, void* d_ws, size_t ws_size,
                              hipStream_t stream) {
    const float* X0  = (const float*)d_in[0];
    const float* W   = (const float*)d_in[1];
    const int*   src = (const int*)d_in[2];
    const int*   dst = (const int*)d_in[3];
    const float* lm  = (const float*)d_in[4];
    float* out = (float*)d_out;

    // Workspace (20.0 MB): cur[NN] | e_src[NE] | norm[NN] | X1[NN*F] | bsum[512]
    int*   cur   = (int*)d_ws;
    int*   e_src = cur + NN;
    float* norm  = (float*)(e_src + NE);
    float* X1    = norm + NN;
    int*   bsum  = (int*)(X1 + (size_t)NN * F);

    const int B = 256;
    hipMemsetAsync(cur, 0, NN * sizeof(int), stream);
    k_deg      <<<(NE + B - 1) / B, B, 0, stream>>>(dst, cur);
    k_norm     <<<(NN + B - 1) / B, B, 0, stream>>>(cur, norm);
    k_bsum     <<<NB, B, 0, stream>>>(cur, bsum);
    k_scan_bsum<<<1, 512, 0, stream>>>(bsum);
    k_scan     <<<NB, B, 0, stream>>>(bsum, cur);
    k_fill     <<<(NE + B - 1) / B, B, 0, stream>>>(src, dst, cur, e_src);

    const int gridG = (NN * F + B - 1) / B;   // 16 lanes per node
    k_prop1<<<gridG, B, 0, stream>>>(cur, e_src, X0, norm, lm, X1);
    k_prop2<<<gridG, B, 0, stream>>>(cur, e_src, X0, X1, norm, lm, W, out);
}